// Round 6
// baseline (237.447 us; speedup 1.0000x reference)
//
#include <hip/hip_runtime.h>
#include <hip/hip_bf16.h>
#include <math.h>

// Problem constants: B=16, C=64, H=W=64, M=4096
#define KS 16
#define CHUNK 256
#define PART_STRIDE 4224            // 4096 S + 64 rsum + 1 T + pad
#define CTRL_OFF (256 * PART_STRIDE)  // float index of control area in ws
#define S_OFF (CTRL_OFF + 512)        // float index of s_area

typedef __attribute__((ext_vector_type(8))) short short8;
typedef __attribute__((ext_vector_type(4))) float floatx4;

__device__ __forceinline__ unsigned short f2bf(float f) {
    __hip_bfloat16 h = __float2bfloat16(f);
    return *reinterpret_cast<unsigned short*>(&h);
}
__device__ __forceinline__ float bf2f(unsigned short h) {
    return __uint_as_float(((unsigned int)h) << 16);
}
// Halfword base of element (r, k=8*kb) in the swizzled fragment layout.
__device__ __forceinline__ int HW(int r, int kb) {
    return ((kb << 6) + (r ^ (kb & 15))) << 3;
}
__device__ __forceinline__ floatx4 mfma_bf16(short8 a, short8 b, floatx4 c) {
    return __builtin_amdgcn_mfma_f32_16x16x32_bf16(a, b, c, 0, 0, 0);
}

// ---------------------------------------------------------------------------
// NS pass helpers, 16 waves (1024 thr). Stored matrices are transposed
// products (valid: all NS iterates symmetric). MODE 0: D=0.5*(3I-P)  1: D=P
// ---------------------------------------------------------------------------
template <int MODE>
__device__ __forceinline__ void pass_single(const unsigned short (*U)[4096],
                                            const unsigned short (*V)[4096],
                                            unsigned short (*D)[4096], int tid) {
    int lane = tid & 63, wv = tid >> 6;
    int g = lane >> 4, rh = lane & 15;
    int ta = wv & 3, tc = wv >> 2;
    floatx4 acc = (floatx4){0.f, 0.f, 0.f, 0.f};
    #pragma unroll
    for (int ks_ = 0; ks_ < 2; ++ks_) {
        int kb = ks_ * 4 + g;
        int ao = HW(16 * ta + rh, kb);
        int bo = HW(16 * tc + rh, kb);
        short8 auh = *reinterpret_cast<const short8*>(&U[0][ao]);
        short8 aul = *reinterpret_cast<const short8*>(&U[1][ao]);
        short8 bvh = *reinterpret_cast<const short8*>(&V[0][bo]);
        short8 bvl = *reinterpret_cast<const short8*>(&V[1][bo]);
        acc = mfma_bf16(auh, bvh, acc);
        acc = mfma_bf16(auh, bvl, acc);
        acc = mfma_bf16(aul, bvh, acc);
    }
    int j = 16 * tc + rh;
    int kbi = 2 * ta + (g >> 1), sub = (g & 1) << 2;
    unsigned short hs[4], ls[4];
    #pragma unroll
    for (int qq = 0; qq < 4; ++qq) {
        int i = 16 * ta + 4 * g + qq;
        float v = acc[qq];
        if (MODE == 0) v = 0.5f * ((i == j ? 3.0f : 0.0f) - v);
        hs[qq] = f2bf(v);
        ls[qq] = f2bf(v - bf2f(hs[qq]));
    }
    int idx = HW(j, kbi) + sub;   // transposed position (j, i)
    uint2 u;
    u.x = hs[0] | ((unsigned)hs[1] << 16); u.y = hs[2] | ((unsigned)hs[3] << 16);
    *reinterpret_cast<uint2*>(&D[0][idx]) = u;
    u.x = ls[0] | ((unsigned)ls[1] << 16); u.y = ls[2] | ((unsigned)ls[3] << 16);
    *reinterpret_cast<uint2*>(&D[1][idx]) = u;
    __syncthreads();
}

// Fused dual pass: waves 0-7 compute DY = Y@W, waves 8-15 compute DZ = W@Z.
__device__ __forceinline__ void pass_fused(const unsigned short (*Y)[4096],
                                           const unsigned short (*W)[4096],
                                           const unsigned short (*Z)[4096],
                                           unsigned short (*DY)[4096],
                                           unsigned short (*DZ)[4096], int tid) {
    int lane = tid & 63, wv = tid >> 6;
    int g = lane >> 4, rh = lane & 15;
    const unsigned short (*U)[4096] = (wv < 8) ? Y : W;
    const unsigned short (*V)[4096] = (wv < 8) ? W : Z;
    unsigned short (*D)[4096] = (wv < 8) ? DY : DZ;
    int w8 = wv & 7;
    int ta0 = (w8 >> 2) << 1, tc = w8 & 3;
    floatx4 acc[2] = {(floatx4){0.f,0.f,0.f,0.f}, (floatx4){0.f,0.f,0.f,0.f}};
    #pragma unroll
    for (int ks_ = 0; ks_ < 2; ++ks_) {
        int kb = ks_ * 4 + g;
        int bo = HW(16 * tc + rh, kb);
        short8 bvh = *reinterpret_cast<const short8*>(&V[0][bo]);
        short8 bvl = *reinterpret_cast<const short8*>(&V[1][bo]);
        #pragma unroll
        for (int a = 0; a < 2; ++a) {
            int ao = HW(16 * (ta0 + a) + rh, kb);
            short8 auh = *reinterpret_cast<const short8*>(&U[0][ao]);
            short8 aul = *reinterpret_cast<const short8*>(&U[1][ao]);
            acc[a] = mfma_bf16(auh, bvh, acc[a]);
            acc[a] = mfma_bf16(auh, bvl, acc[a]);
            acc[a] = mfma_bf16(aul, bvh, acc[a]);
        }
    }
    int j = 16 * tc + rh;
    #pragma unroll
    for (int a = 0; a < 2; ++a) {
        int ta = ta0 + a;
        int kbi = 2 * ta + (g >> 1), sub = (g & 1) << 2;
        unsigned short hs[4], ls[4];
        #pragma unroll
        for (int qq = 0; qq < 4; ++qq) {
            float v = acc[a][qq];
            hs[qq] = f2bf(v);
            ls[qq] = f2bf(v - bf2f(hs[qq]));
        }
        int idx = HW(j, kbi) + sub;
        uint2 u;
        u.x = hs[0] | ((unsigned)hs[1] << 16); u.y = hs[2] | ((unsigned)hs[3] << 16);
        *reinterpret_cast<uint2*>(&D[0][idx]) = u;
        u.x = ls[0] | ((unsigned)ls[1] << 16); u.y = ls[2] | ((unsigned)ls[3] << 16);
        *reinterpret_cast<uint2*>(&D[1][idx]) = u;
    }
    __syncthreads();
}

__device__ __forceinline__ void colsum_stage(const unsigned short (*M)[4096],
                                             float* dst, float* part, int tid) {
    int ii = tid & 63, grp = (tid >> 6) & 7;
    if (tid < 512) {
        int o = HW(ii, grp);
        short8 vh = *reinterpret_cast<const short8*>(&M[0][o]);
        short8 vl = *reinterpret_cast<const short8*>(&M[1][o]);
        float s = 0.f;
        #pragma unroll
        for (int e = 0; e < 8; ++e)
            s += bf2f((unsigned short)vh[e]) + bf2f((unsigned short)vl[e]);
        part[grp * 64 + ii] = s;
    }
    __syncthreads();
    if (tid < 64) {
        float s = 0.f;
        #pragma unroll
        for (int q = 0; q < 8; ++q) s += part[q * 64 + tid];
        dst[tid] = s;
    }
    __syncthreads();
}

__device__ __forceinline__ void matvec_stage(const unsigned short (*M)[4096],
                                             const float* __restrict__ src,
                                             float* dst, float* part, int tid) {
    int ii = tid & 63, grp = (tid >> 6) & 7;
    if (tid < 512) {
        int o = HW(ii, grp);
        short8 vh = *reinterpret_cast<const short8*>(&M[0][o]);
        short8 vl = *reinterpret_cast<const short8*>(&M[1][o]);
        float s = 0.f;
        #pragma unroll
        for (int e = 0; e < 8; ++e)
            s += (bf2f((unsigned short)vh[e]) + bf2f((unsigned short)vl[e])) * src[grp * 8 + e];
        part[grp * 64 + ii] = s;
    }
    __syncthreads();
    if (tid < 64) {
        float s = 0.f;
        #pragma unroll
        for (int q = 0; q < 8; ++q) s += part[q * 64 + tid];
        dst[tid] = s;
    }
    __syncthreads();
}

// ---------------------------------------------------------------------------
// Single kernel, NO grid.sync:
//   A) per-(b,ks) partial Gram (all 256 blocks)
//   finisher election via per-batch atomic counter (last of 16 blocks)
//   C) finisher: reduce -> cov -> NS -> conv chain -> s[b] + release flag
//   D) all blocks: spin on flag[b] (s_sleep backoff), then scale own slice.
// ~86KB LDS => 1 block/CU => all 256 blocks co-resident => spin is safe.
// ---------------------------------------------------------------------------
__global__ __launch_bounds__(1024, 1) void soca_one(const float* __restrict__ x,
                                                    const float* __restrict__ w1,
                                                    const float* __restrict__ b1,
                                                    const float* __restrict__ w2,
                                                    const float* __restrict__ b2,
                                                    float* __restrict__ out,
                                                    float* __restrict__ ws) {
    __shared__ __align__(16) unsigned char big[81920];   // A: xh/xl/csp  C: planes
    __shared__ __align__(16) float auxf[1024];
    __shared__ int isFinSh;
    int bk = blockIdx.x, tid = threadIdx.x;
    int w = tid >> 6, l = tid & 63;
    int b = bk >> 4, ks = bk & 15;
    const float invM = 1.0f / 4096.0f;
    unsigned int* ctrl = (unsigned int*)(ws + CTRL_OFF);  // [0..255] counters, [256..511] flags (64B spaced)
    float* s_area = ws + S_OFF;
    float* outp = ws + (size_t)bk * PART_STRIDE;

    // ================= Phase A: partial Gram for (b, ks) ====================
    {
        unsigned short* xh = (unsigned short*)big;
        unsigned short* xl = xh + 64 * CHUNK;
        float* cspL = (float*)(big + 65536);   // [16][256] per-wave colsum partials
        const float* xb = x + ((size_t)b * 64) * 4096 + ks * CHUNK;

        float cs0 = 0.f, cs1 = 0.f, cs2 = 0.f, cs3 = 0.f;
        #pragma unroll
        for (int r = 0; r < 4; ++r) {
            int c = w * 4 + r;
            float4 v = *reinterpret_cast<const float4*>(xb + (size_t)c * 4096 + l * 4);
            cs0 += v.x; cs1 += v.y; cs2 += v.z; cs3 += v.w;
            float rsp = v.x + v.y + v.z + v.w;      // row-sum partial, wave covers row
            #pragma unroll
            for (int off = 32; off >= 1; off >>= 1) rsp += __shfl_xor(rsp, off, 64);
            if (l == 0) outp[4096 + c] = rsp;
            float vv[4] = {v.x, v.y, v.z, v.w};
            unsigned short hs[4], ls_[4];
            #pragma unroll
            for (int q = 0; q < 4; ++q) {
                hs[q] = f2bf(vv[q]);
                ls_[q] = f2bf(vv[q] - bf2f(hs[q]));
            }
            int idx = HW(c, l >> 1) + ((l & 1) << 2);
            uint2 u;
            u.x = hs[0] | ((unsigned)hs[1] << 16); u.y = hs[2] | ((unsigned)hs[3] << 16);
            *reinterpret_cast<uint2*>(&xh[idx]) = u;
            u.x = ls_[0] | ((unsigned)ls_[1] << 16); u.y = ls_[2] | ((unsigned)ls_[3] << 16);
            *reinterpret_cast<uint2*>(&xl[idx]) = u;
        }
        *reinterpret_cast<float4*>(&cspL[w * 256 + l * 4]) = make_float4(cs0, cs1, cs2, cs3);
        __syncthreads();

        // MFMA Gram: wave w owns tile (ta, tc)
        int g = l >> 4, rh = l & 15;
        int ta = w >> 2, tc = w & 3;
        floatx4 acc = (floatx4){0.f, 0.f, 0.f, 0.f};
        #pragma unroll
        for (int ks_ = 0; ks_ < 8; ++ks_) {
            int kb = ks_ * 4 + g;
            int ao = HW(16 * ta + rh, kb);
            int bo = HW(16 * tc + rh, kb);
            short8 auh = *reinterpret_cast<const short8*>(&xh[ao]);
            short8 aul = *reinterpret_cast<const short8*>(&xl[ao]);
            short8 bvh = *reinterpret_cast<const short8*>(&xh[bo]);
            short8 bvl = *reinterpret_cast<const short8*>(&xl[bo]);
            acc = mfma_bf16(auh, bvh, acc);
            acc = mfma_bf16(auh, bvl, acc);
            acc = mfma_bf16(aul, bvh, acc);
        }
        {   // store S^T position (S symmetric) -> contiguous float4
            int j = 16 * tc + rh, i0 = 16 * ta + 4 * g;
            *reinterpret_cast<float4*>(&outp[j * 64 + i0]) =
                make_float4(acc[0], acc[1], acc[2], acc[3]);
        }
        // T partial = sum_m colsum_m^2
        float* red = auxf;
        if (tid < 256) {
            float cm = 0.f;
            #pragma unroll
            for (int ww = 0; ww < 16; ++ww) cm += cspL[ww * 256 + tid];
            red[tid] = cm * cm;
        }
        __syncthreads();
        for (int st = 128; st > 0; st >>= 1) {
            if (tid < st) red[tid] += red[tid + st];
            __syncthreads();
        }
        if (tid == 0) outp[4160] = red[0];
    }

    // ================= Finisher election ====================================
    __threadfence();
    __syncthreads();
    if (tid == 0) {
        unsigned int old = atomicAdd(&ctrl[b * 16], 1u);
        isFinSh = (old == 15u) ? 1 : 0;
    }
    __syncthreads();

    // ================= Phase C (finisher only): reduce + NS + conv ==========
    if (isFinSh) {
        __threadfence();   // acquire partials written by sibling blocks
        unsigned short (*planes)[2][4096] = (unsigned short (*)[2][4096])big;
        const float* base = ws + (size_t)b * KS * PART_STRIDE;
        float* rsumL = auxf;   // [64]; auxf[64]=T, auxf[65]=normA

        if (tid < 64) {
            float s = 0.f;
            for (int k = 0; k < KS; ++k) s += base[k * PART_STRIDE + 4096 + tid];
            rsumL[tid] = s;
        } else if (tid == 64) {
            float t = 0.f;
            for (int k = 0; k < KS; ++k) t += base[k * PART_STRIDE + 4160];
            auxf[64] = t;
        }
        int e = tid * 4;
        int i = tid >> 4, j0 = (tid & 15) * 4;
        floatx4 s4 = (floatx4){0.f, 0.f, 0.f, 0.f};
        for (int k = 0; k < KS; ++k)
            s4 += *reinterpret_cast<const floatx4*>(base + k * PART_STRIDE + e);
        __syncthreads();
        if (tid == 0) {
            float sr = 0.f;
            for (int q = 0; q < 64; ++q) sr += rsumL[q];
            auxf[65] = (auxf[64] - sr * sr * invM) * invM;   // normA = sum_ij cov
        }
        __syncthreads();
        float normA = auxf[65];
        float invNA = 1.0f / normA;
        float mui = rsumL[i] * invM;
        unsigned short ah[4], al_[4], zh[4], zl[4];
        #pragma unroll
        for (int q = 0; q < 4; ++q) {
            float cv = s4[q] * invM - mui * (rsumL[j0 + q] * invM);
            float a = cv * invNA;
            float z = 0.5f * (((i == j0 + q) ? 3.0f : 0.0f) - a);
            unsigned short h = f2bf(a);
            ah[q] = h; al_[q] = f2bf(a - bf2f(h));
            h = f2bf(z);
            zh[q] = h; zl[q] = f2bf(z - bf2f(h));
        }
        {
            int idx = HW(i, j0 >> 3) + (j0 & 7);
            uint2 u;
            u.x = ah[0] | ((unsigned)ah[1] << 16); u.y = ah[2] | ((unsigned)ah[3] << 16);
            *reinterpret_cast<uint2*>(&planes[0][0][idx]) = u;
            u.x = al_[0] | ((unsigned)al_[1] << 16); u.y = al_[2] | ((unsigned)al_[3] << 16);
            *reinterpret_cast<uint2*>(&planes[0][1][idx]) = u;
            u.x = zh[0] | ((unsigned)zh[1] << 16); u.y = zh[2] | ((unsigned)zh[3] << 16);
            *reinterpret_cast<uint2*>(&planes[1][0][idx]) = u;
            u.x = zl[0] | ((unsigned)zl[1] << 16); u.y = zl[2] | ((unsigned)zl[3] << 16);
            *reinterpret_cast<uint2*>(&planes[1][1][idx]) = u;
        }
        __syncthreads();

        // NS: Y0 = A@Z0; 3x {W=.5(3I-ZY); Y=YW; Z=WZ} with last Z skipped
        pass_single<1>(planes[0], planes[1], planes[2], tid);   // Y0 -> s2
        pass_single<0>(planes[1], planes[2], planes[0], tid);   // W1 -> s0
        pass_fused(planes[2], planes[0], planes[1], planes[3], planes[4], tid); // Y1->s3,Z1->s4
        pass_single<0>(planes[4], planes[3], planes[1], tid);   // W2 -> s1
        pass_fused(planes[3], planes[1], planes[4], planes[2], planes[0], tid); // Y2->s2,Z2->s0
        pass_single<0>(planes[0], planes[2], planes[3], tid);   // W3 -> s3
        pass_single<1>(planes[2], planes[3], planes[4], tid);   // Y3 -> s4

        // Epilogue: r = 3u - Y3(W3(Z2 u)), u = colsum(Y3)
        float* part = auxf;          // 512 (rsumL dead now)
        float* uvec = auxf + 512;
        float* avec = auxf + 576;
        float* pvec = auxf + 640;
        float* wvec = auxf + 704;
        float* ych  = auxf + 768;
        float* hid  = auxf + 832;
        colsum_stage(planes[4], uvec, part, tid);
        matvec_stage(planes[0], uvec, avec, part, tid);   // a = Z2 u
        matvec_stage(planes[3], avec, pvec, part, tid);   // p = W3 a
        matvec_stage(planes[4], pvec, wvec, part, tid);   // w = Y3 p

        if (tid < 64)
            ych[tid] = (3.0f * uvec[tid] - wvec[tid]) * (0.5f / 64.0f) * sqrtf(normA);
        __syncthreads();
        if (tid < 64) {
            float t1 = b1[tid];
            for (int ii = 0; ii < 64; ++ii)
                t1 += w1[(tid * 64 + ii) * 9 + 4] * ych[ii];
            hid[tid] = fmaxf(t1, 0.f);
        }
        __syncthreads();
        if (tid < 64) {
            float t2 = b2[tid];
            for (int ii = 0; ii < 64; ++ii)
                t2 += w2[(tid * 64 + ii) * 9 + 4] * hid[ii];
            float sig = 1.0f / (1.0f + expf(-t2));
            __hip_atomic_store(&s_area[b * 64 + tid], sig,
                               __ATOMIC_RELAXED, __HIP_MEMORY_SCOPE_AGENT);
        }
        __threadfence();
        __syncthreads();
        if (tid == 0)
            __hip_atomic_store(&ctrl[256 + b * 16], 1u,
                               __ATOMIC_RELEASE, __HIP_MEMORY_SCOPE_AGENT);
    }

    // ================= Phase D: spin on flag, then scale own slice ==========
    if (tid == 0) {
        while (__hip_atomic_load(&ctrl[256 + b * 16],
                                 __ATOMIC_ACQUIRE, __HIP_MEMORY_SCOPE_AGENT) == 0u)
            __builtin_amdgcn_s_sleep(16);
    }
    __syncthreads();
    {
        int r = tid >> 4, sub = tid & 15;
        float sv = __hip_atomic_load(&s_area[b * 64 + r],
                                     __ATOMIC_RELAXED, __HIP_MEMORY_SCOPE_AGENT);
        size_t base4 = ((size_t)(b * 64 + r)) * 1024 + ks * 64 + sub * 4;
        const float4* x4 = reinterpret_cast<const float4*>(x);
        float4* o4 = reinterpret_cast<float4*>(out);
        #pragma unroll
        for (int q = 0; q < 4; ++q) {
            float4 v = x4[base4 + q];
            o4[base4 + q] = make_float4(v.x * sv, v.y * sv, v.z * sv, v.w * sv);
        }
    }
}

extern "C" void kernel_launch(void* const* d_in, const int* in_sizes, int n_in,
                              void* d_out, int out_size, void* d_ws, size_t ws_size,
                              hipStream_t stream) {
    const float* x  = (const float*)d_in[0];
    const float* w1 = (const float*)d_in[1];
    const float* b1 = (const float*)d_in[2];
    const float* w2 = (const float*)d_in[3];
    const float* b2 = (const float*)d_in[4];
    float* out = (float*)d_out;
    float* ws  = (float*)d_ws;

    // Zero the counters+flags region (512 uints). Async memset is capture-legal.
    hipMemsetAsync(ws + CTRL_OFF, 0, 2048, stream);
    soca_one<<<dim3(256), dim3(1024), 0, stream>>>(x, w1, b1, w2, b2, out, ws);
}

// Round 8
// 50.832 us; speedup vs baseline: 4.6712x; 4.6712x over previous
//
#include <hip/hip_runtime.h>
#include <hip/hip_bf16.h>
#include <math.h>

// Problem constants: B=16, C=64, H=W=64, M=4096
#define KS 16
#define CHUNK 256
#define PART_STRIDE 4224            // 4096 S + 64 rsum + 1 T + pad
#define CTRL_OFF (256 * PART_STRIDE)  // float index of control area in ws
#define S_OFF (CTRL_OFF + 512)        // float index of s_area

typedef __attribute__((ext_vector_type(8))) short short8;
typedef __attribute__((ext_vector_type(4))) float floatx4;

__device__ __forceinline__ unsigned short f2bf(float f) {
    __hip_bfloat16 h = __float2bfloat16(f);
    return *reinterpret_cast<unsigned short*>(&h);
}
__device__ __forceinline__ float bf2f(unsigned short h) {
    return __uint_as_float(((unsigned int)h) << 16);
}
// Halfword base of element (r, k=8*kb) in the swizzled fragment layout.
__device__ __forceinline__ int HW(int r, int kb) {
    return ((kb << 6) + (r ^ (kb & 15))) << 3;
}
__device__ __forceinline__ floatx4 mfma_bf16(short8 a, short8 b, floatx4 c) {
    return __builtin_amdgcn_mfma_f32_16x16x32_bf16(a, b, c, 0, 0, 0);
}

// ---------------------------------------------------------------------------
// NS pass helpers, 16 waves (1024 thr). Stored matrices are transposed
// products (valid: all NS iterates symmetric). MODE 0: D=0.5*(3I-P)  1: D=P
// ---------------------------------------------------------------------------
template <int MODE>
__device__ __forceinline__ void pass_single(const unsigned short (*U)[4096],
                                            const unsigned short (*V)[4096],
                                            unsigned short (*D)[4096], int tid) {
    int lane = tid & 63, wv = tid >> 6;
    int g = lane >> 4, rh = lane & 15;
    int ta = wv & 3, tc = wv >> 2;
    floatx4 acc = (floatx4){0.f, 0.f, 0.f, 0.f};
    #pragma unroll
    for (int ks_ = 0; ks_ < 2; ++ks_) {
        int kb = ks_ * 4 + g;
        int ao = HW(16 * ta + rh, kb);
        int bo = HW(16 * tc + rh, kb);
        short8 auh = *reinterpret_cast<const short8*>(&U[0][ao]);
        short8 aul = *reinterpret_cast<const short8*>(&U[1][ao]);
        short8 bvh = *reinterpret_cast<const short8*>(&V[0][bo]);
        short8 bvl = *reinterpret_cast<const short8*>(&V[1][bo]);
        acc = mfma_bf16(auh, bvh, acc);
        acc = mfma_bf16(auh, bvl, acc);
        acc = mfma_bf16(aul, bvh, acc);
    }
    int j = 16 * tc + rh;
    int kbi = 2 * ta + (g >> 1), sub = (g & 1) << 2;
    unsigned short hs[4], ls[4];
    #pragma unroll
    for (int qq = 0; qq < 4; ++qq) {
        int i = 16 * ta + 4 * g + qq;
        float v = acc[qq];
        if (MODE == 0) v = 0.5f * ((i == j ? 3.0f : 0.0f) - v);
        hs[qq] = f2bf(v);
        ls[qq] = f2bf(v - bf2f(hs[qq]));
    }
    int idx = HW(j, kbi) + sub;   // transposed position (j, i)
    uint2 u;
    u.x = hs[0] | ((unsigned)hs[1] << 16); u.y = hs[2] | ((unsigned)hs[3] << 16);
    *reinterpret_cast<uint2*>(&D[0][idx]) = u;
    u.x = ls[0] | ((unsigned)ls[1] << 16); u.y = ls[2] | ((unsigned)ls[3] << 16);
    *reinterpret_cast<uint2*>(&D[1][idx]) = u;
    __syncthreads();
}

// Fused dual pass: waves 0-7 compute DY = Y@W, waves 8-15 compute DZ = W@Z.
__device__ __forceinline__ void pass_fused(const unsigned short (*Y)[4096],
                                           const unsigned short (*W)[4096],
                                           const unsigned short (*Z)[4096],
                                           unsigned short (*DY)[4096],
                                           unsigned short (*DZ)[4096], int tid) {
    int lane = tid & 63, wv = tid >> 6;
    int g = lane >> 4, rh = lane & 15;
    const unsigned short (*U)[4096] = (wv < 8) ? Y : W;
    const unsigned short (*V)[4096] = (wv < 8) ? W : Z;
    unsigned short (*D)[4096] = (wv < 8) ? DY : DZ;
    int w8 = wv & 7;
    int ta0 = (w8 >> 2) << 1, tc = w8 & 3;
    floatx4 acc[2] = {(floatx4){0.f,0.f,0.f,0.f}, (floatx4){0.f,0.f,0.f,0.f}};
    #pragma unroll
    for (int ks_ = 0; ks_ < 2; ++ks_) {
        int kb = ks_ * 4 + g;
        int bo = HW(16 * tc + rh, kb);
        short8 bvh = *reinterpret_cast<const short8*>(&V[0][bo]);
        short8 bvl = *reinterpret_cast<const short8*>(&V[1][bo]);
        #pragma unroll
        for (int a = 0; a < 2; ++a) {
            int ao = HW(16 * (ta0 + a) + rh, kb);
            short8 auh = *reinterpret_cast<const short8*>(&U[0][ao]);
            short8 aul = *reinterpret_cast<const short8*>(&U[1][ao]);
            acc[a] = mfma_bf16(auh, bvh, acc[a]);
            acc[a] = mfma_bf16(auh, bvl, acc[a]);
            acc[a] = mfma_bf16(aul, bvh, acc[a]);
        }
    }
    int j = 16 * tc + rh;
    #pragma unroll
    for (int a = 0; a < 2; ++a) {
        int ta = ta0 + a;
        int kbi = 2 * ta + (g >> 1), sub = (g & 1) << 2;
        unsigned short hs[4], ls[4];
        #pragma unroll
        for (int qq = 0; qq < 4; ++qq) {
            float v = acc[a][qq];
            hs[qq] = f2bf(v);
            ls[qq] = f2bf(v - bf2f(hs[qq]));
        }
        int idx = HW(j, kbi) + sub;
        uint2 u;
        u.x = hs[0] | ((unsigned)hs[1] << 16); u.y = hs[2] | ((unsigned)hs[3] << 16);
        *reinterpret_cast<uint2*>(&D[0][idx]) = u;
        u.x = ls[0] | ((unsigned)ls[1] << 16); u.y = ls[2] | ((unsigned)ls[3] << 16);
        *reinterpret_cast<uint2*>(&D[1][idx]) = u;
    }
    __syncthreads();
}

__device__ __forceinline__ void colsum_stage(const unsigned short (*M)[4096],
                                             float* dst, float* part, int tid) {
    int ii = tid & 63, grp = (tid >> 6) & 7;
    if (tid < 512) {
        int o = HW(ii, grp);
        short8 vh = *reinterpret_cast<const short8*>(&M[0][o]);
        short8 vl = *reinterpret_cast<const short8*>(&M[1][o]);
        float s = 0.f;
        #pragma unroll
        for (int e = 0; e < 8; ++e)
            s += bf2f((unsigned short)vh[e]) + bf2f((unsigned short)vl[e]);
        part[grp * 64 + ii] = s;
    }
    __syncthreads();
    if (tid < 64) {
        float s = 0.f;
        #pragma unroll
        for (int q = 0; q < 8; ++q) s += part[q * 64 + tid];
        dst[tid] = s;
    }
    __syncthreads();
}

__device__ __forceinline__ void matvec_stage(const unsigned short (*M)[4096],
                                             const float* __restrict__ src,
                                             float* dst, float* part, int tid) {
    int ii = tid & 63, grp = (tid >> 6) & 7;
    if (tid < 512) {
        int o = HW(ii, grp);
        short8 vh = *reinterpret_cast<const short8*>(&M[0][o]);
        short8 vl = *reinterpret_cast<const short8*>(&M[1][o]);
        float s = 0.f;
        #pragma unroll
        for (int e = 0; e < 8; ++e)
            s += (bf2f((unsigned short)vh[e]) + bf2f((unsigned short)vl[e])) * src[grp * 8 + e];
        part[grp * 64 + ii] = s;
    }
    __syncthreads();
    if (tid < 64) {
        float s = 0.f;
        #pragma unroll
        for (int q = 0; q < 8; ++q) s += part[q * 64 + tid];
        dst[tid] = s;
    }
    __syncthreads();
}

// ---------------------------------------------------------------------------
// Single kernel, flag-based handoff with XCD-aware coherence protocol:
//   - producers: normal stores -> __syncthreads (drains vmcnt) -> tid0:
//     release-device fence (1 wbl2/block) + atomicAdd election
//   - finisher: acquire fence ONCE -> normal reads of partials
//   - s published via relaxed-agent (bypasses L2); flag via release
//   - consumers: RELAXED-agent spin (NO invalidate per poll) + s_sleep
// ~86KB LDS => 1 block/CU => all 256 blocks co-resident => spin is safe.
// ---------------------------------------------------------------------------
__global__ __launch_bounds__(1024, 1) void soca_one(const float* __restrict__ x,
                                                    const float* __restrict__ w1,
                                                    const float* __restrict__ b1,
                                                    const float* __restrict__ w2,
                                                    const float* __restrict__ b2,
                                                    float* __restrict__ out,
                                                    float* __restrict__ ws) {
    __shared__ __align__(16) unsigned char big[81920];   // A: xh/xl/csp  C: planes
    __shared__ __align__(16) float auxf[1024];
    __shared__ int isFinSh;
    int bk = blockIdx.x, tid = threadIdx.x;
    int w = tid >> 6, l = tid & 63;
    int b = bk >> 4, ks = bk & 15;
    const float invM = 1.0f / 4096.0f;
    unsigned int* ctrl = (unsigned int*)(ws + CTRL_OFF);  // [0..255] counters, [256..511] flags (64B spaced)
    float* s_area = ws + S_OFF;
    float* outp = ws + (size_t)bk * PART_STRIDE;

    // ================= Phase A: partial Gram for (b, ks) ====================
    {
        unsigned short* xh = (unsigned short*)big;
        unsigned short* xl = xh + 64 * CHUNK;
        float* cspL = (float*)(big + 65536);   // [16][256] per-wave colsum partials
        const float* xb = x + ((size_t)b * 64) * 4096 + ks * CHUNK;

        float cs0 = 0.f, cs1 = 0.f, cs2 = 0.f, cs3 = 0.f;
        #pragma unroll
        for (int r = 0; r < 4; ++r) {
            int c = w * 4 + r;
            float4 v = *reinterpret_cast<const float4*>(xb + (size_t)c * 4096 + l * 4);
            cs0 += v.x; cs1 += v.y; cs2 += v.z; cs3 += v.w;
            float rsp = v.x + v.y + v.z + v.w;      // row-sum partial, wave covers row
            #pragma unroll
            for (int off = 32; off >= 1; off >>= 1) rsp += __shfl_xor(rsp, off, 64);
            if (l == 0) outp[4096 + c] = rsp;
            float vv[4] = {v.x, v.y, v.z, v.w};
            unsigned short hs[4], ls_[4];
            #pragma unroll
            for (int q = 0; q < 4; ++q) {
                hs[q] = f2bf(vv[q]);
                ls_[q] = f2bf(vv[q] - bf2f(hs[q]));
            }
            int idx = HW(c, l >> 1) + ((l & 1) << 2);
            uint2 u;
            u.x = hs[0] | ((unsigned)hs[1] << 16); u.y = hs[2] | ((unsigned)hs[3] << 16);
            *reinterpret_cast<uint2*>(&xh[idx]) = u;
            u.x = ls_[0] | ((unsigned)ls_[1] << 16); u.y = ls_[2] | ((unsigned)ls_[3] << 16);
            *reinterpret_cast<uint2*>(&xl[idx]) = u;
        }
        *reinterpret_cast<float4*>(&cspL[w * 256 + l * 4]) = make_float4(cs0, cs1, cs2, cs3);
        __syncthreads();

        // MFMA Gram: wave w owns tile (ta, tc)
        int g = l >> 4, rh = l & 15;
        int ta = w >> 2, tc = w & 3;
        floatx4 acc = (floatx4){0.f, 0.f, 0.f, 0.f};
        #pragma unroll
        for (int ks_ = 0; ks_ < 8; ++ks_) {
            int kb = ks_ * 4 + g;
            int ao = HW(16 * ta + rh, kb);
            int bo = HW(16 * tc + rh, kb);
            short8 auh = *reinterpret_cast<const short8*>(&xh[ao]);
            short8 aul = *reinterpret_cast<const short8*>(&xl[ao]);
            short8 bvh = *reinterpret_cast<const short8*>(&xh[bo]);
            short8 bvl = *reinterpret_cast<const short8*>(&xl[bo]);
            acc = mfma_bf16(auh, bvh, acc);
            acc = mfma_bf16(auh, bvl, acc);
            acc = mfma_bf16(aul, bvh, acc);
        }
        {   // store S^T position (S symmetric) -> contiguous float4
            int j = 16 * tc + rh, i0 = 16 * ta + 4 * g;
            *reinterpret_cast<float4*>(&outp[j * 64 + i0]) =
                make_float4(acc[0], acc[1], acc[2], acc[3]);
        }
        // T partial = sum_m colsum_m^2
        float* red = auxf;
        if (tid < 256) {
            float cm = 0.f;
            #pragma unroll
            for (int ww = 0; ww < 16; ++ww) cm += cspL[ww * 256 + tid];
            red[tid] = cm * cm;
        }
        __syncthreads();
        for (int st = 128; st > 0; st >>= 1) {
            if (tid < st) red[tid] += red[tid + st];
            __syncthreads();
        }
        if (tid == 0) outp[4160] = red[0];
    }

    // ================= Finisher election ====================================
    // __syncthreads drains every wave's vmcnt -> all block stores are in L2.
    __syncthreads();
    if (tid == 0) {
        __scoped_atomic_thread_fence(__ATOMIC_RELEASE, __MEMORY_SCOPE_DEVICE); // 1 wbl2
        unsigned int old = __hip_atomic_fetch_add(&ctrl[b * 16], 1u,
                                                  __ATOMIC_RELAXED, __HIP_MEMORY_SCOPE_AGENT);
        isFinSh = (old == 15u) ? 1 : 0;
    }
    __syncthreads();

    // ================= Phase C (finisher only): reduce + NS + conv ==========
    if (isFinSh) {
        // one-time acquire: invalidate this XCD's (possibly stale) L2 copies
        __scoped_atomic_thread_fence(__ATOMIC_ACQUIRE, __MEMORY_SCOPE_DEVICE);
        __syncthreads();
        unsigned short (*planes)[2][4096] = (unsigned short (*)[2][4096])big;
        const float* base = ws + (size_t)b * KS * PART_STRIDE;
        float* rsumL = auxf;   // [64]; auxf[64]=T, auxf[65]=normA

        if (tid < 64) {
            float s = 0.f;
            for (int k = 0; k < KS; ++k) s += base[k * PART_STRIDE + 4096 + tid];
            rsumL[tid] = s;
        } else if (tid == 64) {
            float t = 0.f;
            for (int k = 0; k < KS; ++k) t += base[k * PART_STRIDE + 4160];
            auxf[64] = t;
        }
        int e = tid * 4;
        int i = tid >> 4, j0 = (tid & 15) * 4;
        floatx4 s4 = (floatx4){0.f, 0.f, 0.f, 0.f};
        for (int k = 0; k < KS; ++k)
            s4 += *reinterpret_cast<const floatx4*>(base + k * PART_STRIDE + e);
        __syncthreads();
        if (tid == 0) {
            float sr = 0.f;
            for (int q = 0; q < 64; ++q) sr += rsumL[q];
            auxf[65] = (auxf[64] - sr * sr * invM) * invM;   // normA = sum_ij cov
        }
        __syncthreads();
        float normA = auxf[65];
        float invNA = 1.0f / normA;
        float mui = rsumL[i] * invM;
        unsigned short ah[4], al_[4], zh[4], zl[4];
        #pragma unroll
        for (int q = 0; q < 4; ++q) {
            float cv = s4[q] * invM - mui * (rsumL[j0 + q] * invM);
            float a = cv * invNA;
            float z = 0.5f * (((i == j0 + q) ? 3.0f : 0.0f) - a);
            unsigned short h = f2bf(a);
            ah[q] = h; al_[q] = f2bf(a - bf2f(h));
            h = f2bf(z);
            zh[q] = h; zl[q] = f2bf(z - bf2f(h));
        }
        {
            int idx = HW(i, j0 >> 3) + (j0 & 7);
            uint2 u;
            u.x = ah[0] | ((unsigned)ah[1] << 16); u.y = ah[2] | ((unsigned)ah[3] << 16);
            *reinterpret_cast<uint2*>(&planes[0][0][idx]) = u;
            u.x = al_[0] | ((unsigned)al_[1] << 16); u.y = al_[2] | ((unsigned)al_[3] << 16);
            *reinterpret_cast<uint2*>(&planes[0][1][idx]) = u;
            u.x = zh[0] | ((unsigned)zh[1] << 16); u.y = zh[2] | ((unsigned)zh[3] << 16);
            *reinterpret_cast<uint2*>(&planes[1][0][idx]) = u;
            u.x = zl[0] | ((unsigned)zl[1] << 16); u.y = zl[2] | ((unsigned)zl[3] << 16);
            *reinterpret_cast<uint2*>(&planes[1][1][idx]) = u;
        }
        __syncthreads();

        // NS: Y0 = A@Z0; 3x {W=.5(3I-ZY); Y=YW; Z=WZ} with last Z skipped
        pass_single<1>(planes[0], planes[1], planes[2], tid);   // Y0 -> s2
        pass_single<0>(planes[1], planes[2], planes[0], tid);   // W1 -> s0
        pass_fused(planes[2], planes[0], planes[1], planes[3], planes[4], tid); // Y1->s3,Z1->s4
        pass_single<0>(planes[4], planes[3], planes[1], tid);   // W2 -> s1
        pass_fused(planes[3], planes[1], planes[4], planes[2], planes[0], tid); // Y2->s2,Z2->s0
        pass_single<0>(planes[0], planes[2], planes[3], tid);   // W3 -> s3
        pass_single<1>(planes[2], planes[3], planes[4], tid);   // Y3 -> s4

        // Epilogue: r = 3u - Y3(W3(Z2 u)), u = colsum(Y3)
        float* part = auxf;          // 512 (rsumL dead now)
        float* uvec = auxf + 512;
        float* avec = auxf + 576;
        float* pvec = auxf + 640;
        float* wvec = auxf + 704;
        float* ych  = auxf + 768;
        float* hid  = auxf + 832;
        colsum_stage(planes[4], uvec, part, tid);
        matvec_stage(planes[0], uvec, avec, part, tid);   // a = Z2 u
        matvec_stage(planes[3], avec, pvec, part, tid);   // p = W3 a
        matvec_stage(planes[4], pvec, wvec, part, tid);   // w = Y3 p

        if (tid < 64)
            ych[tid] = (3.0f * uvec[tid] - wvec[tid]) * (0.5f / 64.0f) * sqrtf(normA);
        __syncthreads();
        if (tid < 64) {
            float t1 = b1[tid];
            for (int ii = 0; ii < 64; ++ii)
                t1 += w1[(tid * 64 + ii) * 9 + 4] * ych[ii];
            hid[tid] = fmaxf(t1, 0.f);
        }
        __syncthreads();
        if (tid < 64) {
            float t2 = b2[tid];
            for (int ii = 0; ii < 64; ++ii)
                t2 += w2[(tid * 64 + ii) * 9 + 4] * hid[ii];
            float sig = 1.0f / (1.0f + expf(-t2));
            // relaxed-agent store: bypasses L2, lands at the coherence point
            __hip_atomic_store(&s_area[b * 64 + tid], sig,
                               __ATOMIC_RELAXED, __HIP_MEMORY_SCOPE_AGENT);
        }
        __syncthreads();   // drains wave0's vmcnt -> s stores complete at L3
        if (tid == 0)
            __hip_atomic_store(&ctrl[256 + b * 16], 1u,
                               __ATOMIC_RELEASE, __HIP_MEMORY_SCOPE_AGENT);
    }

    // ================= Phase D: relaxed spin on flag, then scale ============
    if (tid == 0) {
        while (__hip_atomic_load(&ctrl[256 + b * 16],
                                 __ATOMIC_RELAXED, __HIP_MEMORY_SCOPE_AGENT) == 0u)
            __builtin_amdgcn_s_sleep(16);
    }
    __syncthreads();
    {
        int r = tid >> 4, sub = tid & 15;
        // relaxed-agent load: bypasses stale L2, reads the L3-fresh value
        float sv = __hip_atomic_load(&s_area[b * 64 + r],
                                     __ATOMIC_RELAXED, __HIP_MEMORY_SCOPE_AGENT);
        size_t base4 = ((size_t)(b * 64 + r)) * 1024 + ks * 64 + sub * 4;
        const float4* x4 = reinterpret_cast<const float4*>(x);
        float4* o4 = reinterpret_cast<float4*>(out);
        #pragma unroll
        for (int q = 0; q < 4; ++q) {
            float4 v = x4[base4 + q];
            o4[base4 + q] = make_float4(v.x * sv, v.y * sv, v.z * sv, v.w * sv);
        }
    }
}

extern "C" void kernel_launch(void* const* d_in, const int* in_sizes, int n_in,
                              void* d_out, int out_size, void* d_ws, size_t ws_size,
                              hipStream_t stream) {
    const float* x  = (const float*)d_in[0];
    const float* w1 = (const float*)d_in[1];
    const float* b1 = (const float*)d_in[2];
    const float* w2 = (const float*)d_in[3];
    const float* b2 = (const float*)d_in[4];
    float* out = (float*)d_out;
    float* ws  = (float*)d_ws;

    // Zero the counters+flags region (512 uints). Async memset is capture-legal.
    (void)hipMemsetAsync(ws + CTRL_OFF, 0, 2048, stream);
    soca_one<<<dim3(256), dim3(1024), 0, stream>>>(x, w1, b1, w2, b2, out, ws);
}

// Round 9
// 50.803 us; speedup vs baseline: 4.6739x; 1.0006x over previous
//
#include <hip/hip_runtime.h>
#include <hip/hip_bf16.h>
#include <math.h>

// Problem constants: B=16, C=64, H=W=64, M=4096
#define KS 16
#define CHUNK 256
#define PART_STRIDE 4224              // 4096 S + 64 rsum + 1 T + pad
#define CTRL_OFF (256 * PART_STRIDE)  // float index of control area in ws
#define S_OFF (CTRL_OFF + 1024)       // float index of s_area (16 ctrs x 64f spacing)

typedef __attribute__((ext_vector_type(8))) short short8;
typedef __attribute__((ext_vector_type(4))) float floatx4;

__device__ __forceinline__ unsigned short f2bf(float f) {
    __hip_bfloat16 h = __float2bfloat16(f);
    return *reinterpret_cast<unsigned short*>(&h);
}
__device__ __forceinline__ float bf2f(unsigned short h) {
    return __uint_as_float(((unsigned int)h) << 16);
}
// Halfword base of element (r, k=8*kb) in the swizzled fragment layout.
__device__ __forceinline__ int HW(int r, int kb) {
    return ((kb << 6) + (r ^ (kb & 15))) << 3;
}
__device__ __forceinline__ floatx4 mfma_bf16(short8 a, short8 b, floatx4 c) {
    return __builtin_amdgcn_mfma_f32_16x16x32_bf16(a, b, c, 0, 0, 0);
}

// ---------------------------------------------------------------------------
// NS pass helpers, 16 waves (1024 thr). Stored matrices are transposed
// products (valid: all NS iterates symmetric). MODE 0: D=0.5*(3I-P)  1: D=P
// ---------------------------------------------------------------------------
template <int MODE>
__device__ __forceinline__ void pass_single(const unsigned short (*U)[4096],
                                            const unsigned short (*V)[4096],
                                            unsigned short (*D)[4096], int tid) {
    int lane = tid & 63, wv = tid >> 6;
    int g = lane >> 4, rh = lane & 15;
    int ta = wv & 3, tc = wv >> 2;
    floatx4 acc = (floatx4){0.f, 0.f, 0.f, 0.f};
    #pragma unroll
    for (int ks_ = 0; ks_ < 2; ++ks_) {
        int kb = ks_ * 4 + g;
        int ao = HW(16 * ta + rh, kb);
        int bo = HW(16 * tc + rh, kb);
        short8 auh = *reinterpret_cast<const short8*>(&U[0][ao]);
        short8 aul = *reinterpret_cast<const short8*>(&U[1][ao]);
        short8 bvh = *reinterpret_cast<const short8*>(&V[0][bo]);
        short8 bvl = *reinterpret_cast<const short8*>(&V[1][bo]);
        acc = mfma_bf16(auh, bvh, acc);
        acc = mfma_bf16(auh, bvl, acc);
        acc = mfma_bf16(aul, bvh, acc);
    }
    int j = 16 * tc + rh;
    int kbi = 2 * ta + (g >> 1), sub = (g & 1) << 2;
    unsigned short hs[4], ls[4];
    #pragma unroll
    for (int qq = 0; qq < 4; ++qq) {
        int i = 16 * ta + 4 * g + qq;
        float v = acc[qq];
        if (MODE == 0) v = 0.5f * ((i == j ? 3.0f : 0.0f) - v);
        hs[qq] = f2bf(v);
        ls[qq] = f2bf(v - bf2f(hs[qq]));
    }
    int idx = HW(j, kbi) + sub;   // transposed position (j, i)
    uint2 u;
    u.x = hs[0] | ((unsigned)hs[1] << 16); u.y = hs[2] | ((unsigned)hs[3] << 16);
    *reinterpret_cast<uint2*>(&D[0][idx]) = u;
    u.x = ls[0] | ((unsigned)ls[1] << 16); u.y = ls[2] | ((unsigned)ls[3] << 16);
    *reinterpret_cast<uint2*>(&D[1][idx]) = u;
    __syncthreads();
}

// Fused dual pass: waves 0-7 compute DY = Y@W, waves 8-15 compute DZ = W@Z.
__device__ __forceinline__ void pass_fused(const unsigned short (*Y)[4096],
                                           const unsigned short (*W)[4096],
                                           const unsigned short (*Z)[4096],
                                           unsigned short (*DY)[4096],
                                           unsigned short (*DZ)[4096], int tid) {
    int lane = tid & 63, wv = tid >> 6;
    int g = lane >> 4, rh = lane & 15;
    const unsigned short (*U)[4096] = (wv < 8) ? Y : W;
    const unsigned short (*V)[4096] = (wv < 8) ? W : Z;
    unsigned short (*D)[4096] = (wv < 8) ? DY : DZ;
    int w8 = wv & 7;
    int ta0 = (w8 >> 2) << 1, tc = w8 & 3;
    floatx4 acc[2] = {(floatx4){0.f,0.f,0.f,0.f}, (floatx4){0.f,0.f,0.f,0.f}};
    #pragma unroll
    for (int ks_ = 0; ks_ < 2; ++ks_) {
        int kb = ks_ * 4 + g;
        int bo = HW(16 * tc + rh, kb);
        short8 bvh = *reinterpret_cast<const short8*>(&V[0][bo]);
        short8 bvl = *reinterpret_cast<const short8*>(&V[1][bo]);
        #pragma unroll
        for (int a = 0; a < 2; ++a) {
            int ao = HW(16 * (ta0 + a) + rh, kb);
            short8 auh = *reinterpret_cast<const short8*>(&U[0][ao]);
            short8 aul = *reinterpret_cast<const short8*>(&U[1][ao]);
            acc[a] = mfma_bf16(auh, bvh, acc[a]);
            acc[a] = mfma_bf16(auh, bvl, acc[a]);
            acc[a] = mfma_bf16(aul, bvh, acc[a]);
        }
    }
    int j = 16 * tc + rh;
    #pragma unroll
    for (int a = 0; a < 2; ++a) {
        int ta = ta0 + a;
        int kbi = 2 * ta + (g >> 1), sub = (g & 1) << 2;
        unsigned short hs[4], ls[4];
        #pragma unroll
        for (int qq = 0; qq < 4; ++qq) {
            float v = acc[a][qq];
            hs[qq] = f2bf(v);
            ls[qq] = f2bf(v - bf2f(hs[qq]));
        }
        int idx = HW(j, kbi) + sub;
        uint2 u;
        u.x = hs[0] | ((unsigned)hs[1] << 16); u.y = hs[2] | ((unsigned)hs[3] << 16);
        *reinterpret_cast<uint2*>(&D[0][idx]) = u;
        u.x = ls[0] | ((unsigned)ls[1] << 16); u.y = ls[2] | ((unsigned)ls[3] << 16);
        *reinterpret_cast<uint2*>(&D[1][idx]) = u;
    }
    __syncthreads();
}

__device__ __forceinline__ void colsum_stage(const unsigned short (*M)[4096],
                                             float* dst, float* part, int tid) {
    int ii = tid & 63, grp = (tid >> 6) & 7;
    if (tid < 512) {
        int o = HW(ii, grp);
        short8 vh = *reinterpret_cast<const short8*>(&M[0][o]);
        short8 vl = *reinterpret_cast<const short8*>(&M[1][o]);
        float s = 0.f;
        #pragma unroll
        for (int e = 0; e < 8; ++e)
            s += bf2f((unsigned short)vh[e]) + bf2f((unsigned short)vl[e]);
        part[grp * 64 + ii] = s;
    }
    __syncthreads();
    if (tid < 64) {
        float s = 0.f;
        #pragma unroll
        for (int q = 0; q < 8; ++q) s += part[q * 64 + tid];
        dst[tid] = s;
    }
    __syncthreads();
}

__device__ __forceinline__ void matvec_stage(const unsigned short (*M)[4096],
                                             const float* __restrict__ src,
                                             float* dst, float* part, int tid) {
    int ii = tid & 63, grp = (tid >> 6) & 7;
    if (tid < 512) {
        int o = HW(ii, grp);
        short8 vh = *reinterpret_cast<const short8*>(&M[0][o]);
        short8 vl = *reinterpret_cast<const short8*>(&M[1][o]);
        float s = 0.f;
        #pragma unroll
        for (int e = 0; e < 8; ++e)
            s += (bf2f((unsigned short)vh[e]) + bf2f((unsigned short)vl[e])) * src[grp * 8 + e];
        part[grp * 64 + ii] = s;
    }
    __syncthreads();
    if (tid < 64) {
        float s = 0.f;
        #pragma unroll
        for (int q = 0; q < 8; ++q) s += part[q * 64 + tid];
        dst[tid] = s;
    }
    __syncthreads();
}

// ---------------------------------------------------------------------------
// K1: Gram partials (all 256 blocks) + finisher election (atomic, round-8
// protocol) + finisher-only reduce -> NS -> conv -> s_area. No flags, no
// spin: the kernel boundary publishes s_area to the scale kernel.
// ---------------------------------------------------------------------------
__global__ __launch_bounds__(1024, 1) void soca_main(const float* __restrict__ x,
                                                     const float* __restrict__ w1,
                                                     const float* __restrict__ b1,
                                                     const float* __restrict__ w2,
                                                     const float* __restrict__ b2,
                                                     float* __restrict__ ws) {
    __shared__ __align__(16) unsigned char big[81920];   // A: xh/xl/csp  C: planes
    __shared__ __align__(16) float auxf[1024];
    __shared__ float w1t[4096];   // taps [i][o]
    __shared__ float w2t[4096];
    __shared__ int isFinSh;
    int bk = blockIdx.x, tid = threadIdx.x;
    int w = tid >> 6, l = tid & 63;
    int b = bk >> 4, ks = bk & 15;
    const float invM = 1.0f / 4096.0f;
    unsigned int* ctrl = (unsigned int*)(ws + CTRL_OFF);  // ctr b at ctrl[b*64]
    float* s_area = ws + S_OFF;
    float* outp = ws + (size_t)bk * PART_STRIDE;

    // ================= Phase A: partial Gram for (b, ks) ====================
    {
        unsigned short* xh = (unsigned short*)big;
        unsigned short* xl = xh + 64 * CHUNK;
        float* cspL = (float*)(big + 65536);   // [16][256] per-wave colsum partials
        const float* xb = x + ((size_t)b * 64) * 4096 + ks * CHUNK;

        float cs0 = 0.f, cs1 = 0.f, cs2 = 0.f, cs3 = 0.f;
        #pragma unroll
        for (int r = 0; r < 4; ++r) {
            int c = w * 4 + r;
            float4 v = *reinterpret_cast<const float4*>(xb + (size_t)c * 4096 + l * 4);
            cs0 += v.x; cs1 += v.y; cs2 += v.z; cs3 += v.w;
            float rsp = v.x + v.y + v.z + v.w;      // row-sum partial, wave covers row
            #pragma unroll
            for (int off = 32; off >= 1; off >>= 1) rsp += __shfl_xor(rsp, off, 64);
            if (l == 0) outp[4096 + c] = rsp;
            float vv[4] = {v.x, v.y, v.z, v.w};
            unsigned short hs[4], ls_[4];
            #pragma unroll
            for (int q = 0; q < 4; ++q) {
                hs[q] = f2bf(vv[q]);
                ls_[q] = f2bf(vv[q] - bf2f(hs[q]));
            }
            int idx = HW(c, l >> 1) + ((l & 1) << 2);
            uint2 u;
            u.x = hs[0] | ((unsigned)hs[1] << 16); u.y = hs[2] | ((unsigned)hs[3] << 16);
            *reinterpret_cast<uint2*>(&xh[idx]) = u;
            u.x = ls_[0] | ((unsigned)ls_[1] << 16); u.y = ls_[2] | ((unsigned)ls_[3] << 16);
            *reinterpret_cast<uint2*>(&xl[idx]) = u;
        }
        *reinterpret_cast<float4*>(&cspL[w * 256 + l * 4]) = make_float4(cs0, cs1, cs2, cs3);
        __syncthreads();

        // MFMA Gram: wave w owns tile (ta, tc)
        int g = l >> 4, rh = l & 15;
        int ta = w >> 2, tc = w & 3;
        floatx4 acc = (floatx4){0.f, 0.f, 0.f, 0.f};
        #pragma unroll
        for (int ks_ = 0; ks_ < 8; ++ks_) {
            int kb = ks_ * 4 + g;
            int ao = HW(16 * ta + rh, kb);
            int bo = HW(16 * tc + rh, kb);
            short8 auh = *reinterpret_cast<const short8*>(&xh[ao]);
            short8 aul = *reinterpret_cast<const short8*>(&xl[ao]);
            short8 bvh = *reinterpret_cast<const short8*>(&xh[bo]);
            short8 bvl = *reinterpret_cast<const short8*>(&xl[bo]);
            acc = mfma_bf16(auh, bvh, acc);
            acc = mfma_bf16(auh, bvl, acc);
            acc = mfma_bf16(aul, bvh, acc);
        }
        {   // store S^T position (S symmetric) -> contiguous float4
            int j = 16 * tc + rh, i0 = 16 * ta + 4 * g;
            *reinterpret_cast<float4*>(&outp[j * 64 + i0]) =
                make_float4(acc[0], acc[1], acc[2], acc[3]);
        }
        // T partial = sum_m colsum_m^2
        float* red = auxf;
        if (tid < 256) {
            float cm = 0.f;
            #pragma unroll
            for (int ww = 0; ww < 16; ++ww) cm += cspL[ww * 256 + tid];
            red[tid] = cm * cm;
        }
        __syncthreads();
        for (int st = 128; st > 0; st >>= 1) {
            if (tid < st) red[tid] += red[tid + st];
            __syncthreads();
        }
        if (tid == 0) outp[4160] = red[0];
    }

    // ================= Finisher election (round-8 proven protocol) ==========
    __syncthreads();   // drains every wave's vmcnt -> block's stores are in L2
    if (tid == 0) {
        __scoped_atomic_thread_fence(__ATOMIC_RELEASE, __MEMORY_SCOPE_DEVICE);
        unsigned int old = __hip_atomic_fetch_add(&ctrl[b * 64], 1u,
                                                  __ATOMIC_RELAXED, __HIP_MEMORY_SCOPE_AGENT);
        isFinSh = (old == 15u) ? 1 : 0;
    }
    __syncthreads();
    if (!isFinSh) return;   // non-finishers exit; kernel boundary does the rest

    // ================= Phase C (finisher only): reduce + NS + conv ==========
    __scoped_atomic_thread_fence(__ATOMIC_ACQUIRE, __MEMORY_SCOPE_DEVICE);
    __syncthreads();
    {
        // stage conv center taps [i][o] into LDS with all 1024 threads
        #pragma unroll
        for (int t = tid; t < 4096; t += 1024) {
            int i = t >> 6, o = t & 63;
            w1t[t] = w1[(o * 64 + i) * 9 + 4];
            w2t[t] = w2[(o * 64 + i) * 9 + 4];
        }
    }
    unsigned short (*planes)[2][4096] = (unsigned short (*)[2][4096])big;
    const float* base = ws + (size_t)b * KS * PART_STRIDE;
    float* rsumL = auxf;   // [64]; auxf[64]=T, auxf[65]=normA

    if (tid < 64) {
        float s = 0.f;
        for (int k = 0; k < KS; ++k) s += base[k * PART_STRIDE + 4096 + tid];
        rsumL[tid] = s;
    } else if (tid == 64) {
        float t = 0.f;
        for (int k = 0; k < KS; ++k) t += base[k * PART_STRIDE + 4160];
        auxf[64] = t;
    }
    int e = tid * 4;
    int i = tid >> 4, j0 = (tid & 15) * 4;
    floatx4 s4 = (floatx4){0.f, 0.f, 0.f, 0.f};
    for (int k = 0; k < KS; ++k)
        s4 += *reinterpret_cast<const floatx4*>(base + k * PART_STRIDE + e);
    __syncthreads();
    if (tid == 0) {
        float sr = 0.f;
        for (int q = 0; q < 64; ++q) sr += rsumL[q];
        auxf[65] = (auxf[64] - sr * sr * invM) * invM;   // normA = sum_ij cov
    }
    __syncthreads();
    float normA = auxf[65];
    float invNA = 1.0f / normA;
    float mui = rsumL[i] * invM;
    unsigned short ah[4], al_[4], zh[4], zl[4];
    #pragma unroll
    for (int q = 0; q < 4; ++q) {
        float cv = s4[q] * invM - mui * (rsumL[j0 + q] * invM);
        float a = cv * invNA;
        float z = 0.5f * (((i == j0 + q) ? 3.0f : 0.0f) - a);
        unsigned short h = f2bf(a);
        ah[q] = h; al_[q] = f2bf(a - bf2f(h));
        h = f2bf(z);
        zh[q] = h; zl[q] = f2bf(z - bf2f(h));
    }
    {
        int idx = HW(i, j0 >> 3) + (j0 & 7);
        uint2 u;
        u.x = ah[0] | ((unsigned)ah[1] << 16); u.y = ah[2] | ((unsigned)ah[3] << 16);
        *reinterpret_cast<uint2*>(&planes[0][0][idx]) = u;
        u.x = al_[0] | ((unsigned)al_[1] << 16); u.y = al_[2] | ((unsigned)al_[3] << 16);
        *reinterpret_cast<uint2*>(&planes[0][1][idx]) = u;
        u.x = zh[0] | ((unsigned)zh[1] << 16); u.y = zh[2] | ((unsigned)zh[3] << 16);
        *reinterpret_cast<uint2*>(&planes[1][0][idx]) = u;
        u.x = zl[0] | ((unsigned)zl[1] << 16); u.y = zl[2] | ((unsigned)zl[3] << 16);
        *reinterpret_cast<uint2*>(&planes[1][1][idx]) = u;
    }
    __syncthreads();

    // NS: Y0 = A@Z0; 3x {W=.5(3I-ZY); Y=YW; Z=WZ} with last Z skipped
    pass_single<1>(planes[0], planes[1], planes[2], tid);   // Y0 -> s2
    pass_single<0>(planes[1], planes[2], planes[0], tid);   // W1 -> s0
    pass_fused(planes[2], planes[0], planes[1], planes[3], planes[4], tid); // Y1->s3,Z1->s4
    pass_single<0>(planes[4], planes[3], planes[1], tid);   // W2 -> s1
    pass_fused(planes[3], planes[1], planes[4], planes[2], planes[0], tid); // Y2->s2,Z2->s0
    pass_single<0>(planes[0], planes[2], planes[3], tid);   // W3 -> s3
    pass_single<1>(planes[2], planes[3], planes[4], tid);   // Y3 -> s4

    // Epilogue: r = 3u - Y3(W3(Z2 u)), u = colsum(Y3)
    float* part = auxf;          // 512 (rsumL dead now)
    float* uvec = auxf + 512;
    float* avec = auxf + 576;
    float* pvec = auxf + 640;
    float* wvec = auxf + 704;
    float* ych  = auxf + 768;
    float* hid  = auxf + 832;
    colsum_stage(planes[4], uvec, part, tid);
    matvec_stage(planes[0], uvec, avec, part, tid);   // a = Z2 u
    matvec_stage(planes[3], avec, pvec, part, tid);   // p = W3 a
    matvec_stage(planes[4], pvec, wvec, part, tid);   // w = Y3 p

    if (tid < 64)
        ych[tid] = (3.0f * uvec[tid] - wvec[tid]) * (0.5f / 64.0f) * sqrtf(normA);
    __syncthreads();
    if (tid < 64) {
        float t1 = b1[tid];
        for (int ii = 0; ii < 64; ++ii) t1 += w1t[ii * 64 + tid] * ych[ii];
        hid[tid] = fmaxf(t1, 0.f);
    }
    __syncthreads();
    if (tid < 64) {
        float t2 = b2[tid];
        for (int ii = 0; ii < 64; ++ii) t2 += w2t[ii * 64 + tid] * hid[ii];
        s_area[b * 64 + tid] = 1.0f / (1.0f + expf(-t2));   // normal store
    }
}

// ---------------------------------------------------------------------------
// K2: out[b,c,h,w] = s[b,c] * x[b,c,h,w], float4 grid-stride
// ---------------------------------------------------------------------------
__global__ __launch_bounds__(256) void scale_kernel(const float* __restrict__ x,
                                                    const float* __restrict__ s,
                                                    float* __restrict__ out, int n4) {
    int idx = blockIdx.x * 256 + threadIdx.x;
    int stride = gridDim.x * 256;
    for (int f = idx; f < n4; f += stride) {
        float sv = s[f >> 10];
        float4 v = reinterpret_cast<const float4*>(x)[f];
        reinterpret_cast<float4*>(out)[f] = make_float4(v.x * sv, v.y * sv, v.z * sv, v.w * sv);
    }
}

extern "C" void kernel_launch(void* const* d_in, const int* in_sizes, int n_in,
                              void* d_out, int out_size, void* d_ws, size_t ws_size,
                              hipStream_t stream) {
    const float* x  = (const float*)d_in[0];
    const float* w1 = (const float*)d_in[1];
    const float* b1 = (const float*)d_in[2];
    const float* w2 = (const float*)d_in[3];
    const float* b2 = (const float*)d_in[4];
    float* out = (float*)d_out;
    float* ws  = (float*)d_ws;

    // Zero the election counters (16 x 64 floats spacing = 4KB).
    (void)hipMemsetAsync(ws + CTRL_OFF, 0, 4096, stream);
    soca_main<<<dim3(256), dim3(1024), 0, stream>>>(x, w1, b1, w2, b2, ws);
    scale_kernel<<<dim3(2048), dim3(256), 0, stream>>>(x, ws + S_OFF, out, 1048576);
}